// Round 1
// baseline (2434.701 us; speedup 1.0000x reference)
//
#include <hip/hip_runtime.h>
#include <stdint.h>

typedef unsigned short u16;
typedef unsigned int u32;
typedef unsigned char u8;

typedef __attribute__((ext_vector_type(4))) float f32x4;
typedef __attribute__((ext_vector_type(4))) u32 u32x4;
typedef __attribute__((ext_vector_type(8))) __bf16 bf16x8;

#define NITER 48
#define BM 128
#define BN 64
#define KT 32
#define STR 40            // padded LDS row stride in u16 elements (32 data + 8 pad)
#define AXO 0
#define AHO (128*STR)     // 5120
#define BIO (2*128*STR)   // 10240
#define BHO (2*128*STR + 192*STR) // 17920
#define LBUF (2*128*STR + 2*192*STR) // 25600 u16 per buffer

__device__ __forceinline__ u16 f2bf(float f){
    u32 u = __builtin_bit_cast(u32, f);
    u = (u + 0x7FFFu + ((u >> 16) & 1u)) >> 16;
    return (u16)u;
}

__device__ __forceinline__ void store8bf(u16* dst, f32x4 a, f32x4 b){
    u32x4 u;
    u[0] = (u32)f2bf(a[0]) | ((u32)f2bf(a[1]) << 16);
    u[1] = (u32)f2bf(a[2]) | ((u32)f2bf(a[3]) << 16);
    u[2] = (u32)f2bf(b[0]) | ((u32)f2bf(b[1]) << 16);
    u[3] = (u32)f2bf(b[2]) | ((u32)f2bf(b[3]) << 16);
    *(u32x4*)dst = u;
}

// ---------- resets dtype detection: 0=int32, 1=bytes(bool), 2=float32 ----------
__global__ void k_detect(const u8* __restrict__ r, int* __restrict__ flag){
    __shared__ int nz[4];
    if (threadIdx.x < 4) nz[threadIdx.x] = 0;
    __syncthreads();
    int loc[4] = {0,0,0,0};
    const int base = threadIdx.x * 16;
    #pragma unroll
    for (int i = 0; i < 16; ++i) if (r[base + i]) loc[i & 3] = 1;
    #pragma unroll
    for (int j = 0; j < 4; ++j) if (loc[j]) atomicOr(&nz[j], 1);
    __syncthreads();
    if (threadIdx.x == 0){
        int f;
        if (nz[0] && !nz[1] && !nz[2] && !nz[3]) f = 0;          // int32 0/1
        else if (!nz[0] && !nz[1] && (nz[2] || nz[3])) f = 2;    // float32 0/1
        else f = 1;                                              // raw bytes
        *flag = f;
    }
}

__device__ __forceinline__ int reset_at(const void* r, int f, int idx){
    if (f == 0) return ((const int*)r)[idx] != 0;
    if (f == 1) return ((const u8*)r)[idx] != 0;
    return ((const float*)r)[idx] != 0.f;
}

// ---------- age computation + histogram ----------
__global__ void k_ages(const void* __restrict__ resets, const int* __restrict__ flag,
                       u8* __restrict__ age, int* __restrict__ counts){
    __shared__ int lc[NITER];
    const int tid = threadIdx.x;
    if (tid < NITER) lc[tid] = 0;
    __syncthreads();
    const int id = blockIdx.x * 256 + tid;
    const int f = *flag;
    const int t = id >> 7, b = id & 127;
    int a = 0, tt = t;
    while (tt > 0 && !reset_at(resets, f, tt * 128 + b)){ ++a; --tt; }
    if (a > NITER - 1) a = NITER - 1;
    age[id] = (u8)a;
    atomicAdd(&lc[a], 1);
    __syncthreads();
    if (tid < NITER && lc[tid]) atomicAdd(&counts[tid], lc[tid]);
}

__global__ void k_offsets(const int* __restrict__ counts, int* __restrict__ offs,
                          int* __restrict__ curs){
    if (threadIdx.x == 0){
        int o = 0;
        for (int i = 0; i < NITER; ++i){ offs[i] = o; curs[i] = o; o += counts[i]; }
        offs[NITER] = o;
    }
}

__global__ void k_scatter(const u8* __restrict__ age, int* __restrict__ curs,
                          int* __restrict__ list){
    __shared__ int lc[NITER], lb[NITER];
    const int tid = threadIdx.x;
    if (tid < NITER) lc[tid] = 0;
    __syncthreads();
    const int id = blockIdx.x * 256 + tid;
    const int a = age[id];
    const int lpos = atomicAdd(&lc[a], 1);
    __syncthreads();
    if (tid < NITER && lc[tid]) lb[tid] = atomicAdd(&curs[tid], lc[tid]);
    __syncthreads();
    list[lb[a] + lpos] = id;
}

// ---------- weight pack: Wt[n][k] = bf16(W[k][n]), n<3072, k<1024 ----------
__global__ void k_packT(const float* __restrict__ Wi, const float* __restrict__ Wh,
                        u16* __restrict__ Wit, u16* __restrict__ Wht){
    __shared__ float tl[32][33];
    const int kb = blockIdx.x * 32;
    const int nb = blockIdx.y * 32;
    const float* W = blockIdx.z ? Wh : Wi;
    u16* Wt = blockIdx.z ? Wht : Wit;
    const int tx = threadIdx.x;
    for (int r = threadIdx.y; r < 32; r += 8)
        tl[r][tx] = W[(size_t)(kb + r) * 3072 + nb + tx];
    __syncthreads();
    for (int r = threadIdx.y; r < 32; r += 8)
        Wt[(size_t)(nb + r) * 1024 + kb + tx] = f2bf(tl[tx][r]);
}

// ---------- main wavefront GEMM + fused GRU gates ----------
__global__ __launch_bounds__(512, 2)
void k_scan(int iter, const int* __restrict__ list, const int* __restrict__ offs,
            const int* __restrict__ counts, const float* __restrict__ ins,
            float* ys, const u16* __restrict__ Wit, const u16* __restrict__ Wht,
            const float* __restrict__ bi, const float* __restrict__ bhn)
{
    const int count = counts[iter];
    if (count <= 0) return;
    const int off = offs[iter];
    const int nMt = (count + BM - 1) / BM;
    const int nTiles = nMt * 16;
    const bool hasH = (iter > 0);

    __shared__ __align__(16) u16 lds[2][LBUF];

    const int tid = threadIdx.x;
    const int lane = tid & 63;
    const int w = tid >> 6;
    const int wr = w >> 1;          // 0..3
    const int wc = w & 1;           // 0..1
    const int l15 = lane & 15;
    const int l4 = lane >> 4;
    const int ko = 8 * l4;

    const int s_row = tid >> 2;     // 0..127 (A staging row)
    const int s_q = tid & 3;        // 8 floats each

    for (int tile = blockIdx.x; tile < nTiles; tile += gridDim.x){
        const int mt = tile >> 4;
        const int g = tile & 15;
        const int m0 = mt * BM;
        const int c0 = g * BN;

        const int prA = list[off + min(m0 + s_row, count - 1)];
        const float* srcX = ins + (size_t)prA * 1024;
        const float* srcH = ys + (ptrdiff_t)(prA - 128) * 1024;

        f32x4 acc[6][2][2];
        #pragma unroll
        for (int i = 0; i < 6; ++i)
            #pragma unroll
            for (int a2 = 0; a2 < 2; ++a2)
                #pragma unroll
                for (int b2 = 0; b2 < 2; ++b2)
                    acc[i][a2][b2] = (f32x4){0.f, 0.f, 0.f, 0.f};

        // ---- prologue: stage k-tile 0 into lds[0]
        {
            f32x4 x0 = *(const f32x4*)(srcX + s_q * 8);
            f32x4 x1 = *(const f32x4*)(srcX + s_q * 8 + 4);
            store8bf(&lds[0][AXO + s_row * STR + s_q * 8], x0, x1);
            if (hasH){
                f32x4 h0 = *(const f32x4*)(srcH + s_q * 8);
                f32x4 h1 = *(const f32x4*)(srcH + s_q * 8 + 4);
                store8bf(&lds[0][AHO + s_row * STR + s_q * 8], h0, h1);
            }
            const int rA = tid >> 2, qA = tid & 3;
            const size_t iA = (size_t)((rA >> 6) * 1024 + c0 + (rA & 63)) * 1024 + qA * 8;
            *(u32x4*)&lds[0][BIO + rA * STR + qA * 8] = *(const u32x4*)(Wit + iA);
            if (hasH) *(u32x4*)&lds[0][BHO + rA * STR + qA * 8] = *(const u32x4*)(Wht + iA);
            if (tid < 256){
                const size_t iB = (size_t)(2048 + c0 + (tid >> 2)) * 1024 + (tid & 3) * 8;
                *(u32x4*)&lds[0][BIO + (128 + (tid >> 2)) * STR + (tid & 3) * 8] = *(const u32x4*)(Wit + iB);
                if (hasH)
                    *(u32x4*)&lds[0][BHO + (128 + (tid >> 2)) * STR + (tid & 3) * 8] = *(const u32x4*)(Wht + iB);
            }
        }
        __syncthreads();

        int cur = 0;
        #pragma unroll 2
        for (int kt = 0; kt < 32; ++kt){
            // issue next k-tile's global loads early (latency hides under MFMA)
            f32x4 nx0, nx1, nh0, nh1;
            u32x4 nbi0, nbi1, nbh0, nbh1;
            const bool more = (kt < 31);
            if (more){
                const int kn = (kt + 1) * KT;
                nx0 = *(const f32x4*)(srcX + kn + s_q * 8);
                nx1 = *(const f32x4*)(srcX + kn + s_q * 8 + 4);
                if (hasH){
                    nh0 = *(const f32x4*)(srcH + kn + s_q * 8);
                    nh1 = *(const f32x4*)(srcH + kn + s_q * 8 + 4);
                }
                const int rA = tid >> 2, qA = tid & 3;
                const size_t iA = (size_t)((rA >> 6) * 1024 + c0 + (rA & 63)) * 1024 + kn + qA * 8;
                nbi0 = *(const u32x4*)(Wit + iA);
                if (hasH) nbh0 = *(const u32x4*)(Wht + iA);
                if (tid < 256){
                    const size_t iB = (size_t)(2048 + c0 + (tid >> 2)) * 1024 + kn + (tid & 3) * 8;
                    nbi1 = *(const u32x4*)(Wit + iB);
                    if (hasH) nbh1 = *(const u32x4*)(Wht + iB);
                }
            }

            // compute current k-tile
            const u16* L = lds[cur];
            bf16x8 ax[2], ah[2];
            #pragma unroll
            for (int rf = 0; rf < 2; ++rf)
                ax[rf] = *(const bf16x8*)&L[AXO + (wr * 32 + rf * 16 + l15) * STR + ko];
            if (hasH){
                #pragma unroll
                for (int rf = 0; rf < 2; ++rf)
                    ah[rf] = *(const bf16x8*)&L[AHO + (wr * 32 + rf * 16 + l15) * STR + ko];
            }
            #pragma unroll
            for (int gi = 0; gi < 3; ++gi){
                #pragma unroll
                for (int cf = 0; cf < 2; ++cf){
                    const int brow = gi * 64 + wc * 32 + cf * 16 + l15;
                    bf16x8 bv = *(const bf16x8*)&L[BIO + brow * STR + ko];
                    acc[gi][0][cf] = __builtin_amdgcn_mfma_f32_16x16x32_bf16(ax[0], bv, acc[gi][0][cf], 0, 0, 0);
                    acc[gi][1][cf] = __builtin_amdgcn_mfma_f32_16x16x32_bf16(ax[1], bv, acc[gi][1][cf], 0, 0, 0);
                    if (hasH){
                        bf16x8 bh = *(const bf16x8*)&L[BHO + brow * STR + ko];
                        acc[3 + gi][0][cf] = __builtin_amdgcn_mfma_f32_16x16x32_bf16(ah[0], bh, acc[3 + gi][0][cf], 0, 0, 0);
                        acc[3 + gi][1][cf] = __builtin_amdgcn_mfma_f32_16x16x32_bf16(ah[1], bh, acc[3 + gi][1][cf], 0, 0, 0);
                    }
                }
            }

            // write staged data into the other buffer
            if (more){
                u16* N = lds[cur ^ 1];
                store8bf(&N[AXO + s_row * STR + s_q * 8], nx0, nx1);
                if (hasH) store8bf(&N[AHO + s_row * STR + s_q * 8], nh0, nh1);
                const int rA = tid >> 2, qA = tid & 3;
                *(u32x4*)&N[BIO + rA * STR + qA * 8] = nbi0;
                if (hasH) *(u32x4*)&N[BHO + rA * STR + qA * 8] = nbh0;
                if (tid < 256){
                    *(u32x4*)&N[BIO + (128 + (tid >> 2)) * STR + (tid & 3) * 8] = nbi1;
                    if (hasH) *(u32x4*)&N[BHO + (128 + (tid >> 2)) * STR + (tid & 3) * 8] = nbh1;
                }
            }
            __syncthreads();
            cur ^= 1;
        }

        // ---- epilogue: fused GRU gates + output write
        #pragma unroll
        for (int cf = 0; cf < 2; ++cf){
            const int colh = c0 + wc * 32 + cf * 16 + l15;
            const float b_r = bi[colh];
            const float b_z = bi[1024 + colh];
            const float b_n = bi[2048 + colh];
            const float b_h = bhn[colh];
            #pragma unroll
            for (int rf = 0; rf < 2; ++rf){
                #pragma unroll
                for (int m = 0; m < 4; ++m){
                    const int rloc = wr * 32 + rf * 16 + l4 * 4 + m;
                    const int p = list[off + min(m0 + rloc, count - 1)];
                    const float xr = acc[0][rf][cf][m] + b_r;
                    const float xz = acc[1][rf][cf][m] + b_z;
                    const float xn = acc[2][rf][cf][m] + b_n;
                    const float rr = 1.f / (1.f + __expf(-(xr + acc[3][rf][cf][m])));
                    const float zz = 1.f / (1.f + __expf(-(xz + acc[4][rf][cf][m])));
                    const float nn = tanhf(xn + rr * (acc[5][rf][cf][m] + b_h));
                    float hp = 0.f;
                    if (hasH) hp = ys[(size_t)(p - 128) * 1024 + colh];
                    ys[(size_t)p * 1024 + colh] = (1.f - zz) * nn + zz * hp;
                }
            }
        }
    }
}

extern "C" void kernel_launch(void* const* d_in, const int* in_sizes, int n_in,
                              void* d_out, int out_size, void* d_ws, size_t ws_size,
                              hipStream_t stream)
{
    (void)in_sizes; (void)n_in; (void)out_size; (void)ws_size;
    const float* ins  = (const float*)d_in[0];
    const void*  rst  = d_in[1];
    const float* Wi   = (const float*)d_in[2];
    const float* bi   = (const float*)d_in[3];
    const float* Wh   = (const float*)d_in[4];
    const float* bhn  = (const float*)d_in[5];
    float* ys = (float*)d_out;
    u8* ws = (u8*)d_ws;

    u16* Wit    = (u16*)(ws + 0);
    u16* Wht    = (u16*)(ws + 6291456);
    u8*  age    = ws + 12582912;
    int* counts = (int*)(ws + 12648448);
    int* flag   = (int*)(ws + 12648448 + 192);
    int* offs   = (int*)(ws + 12648448 + 256);
    int* curs   = (int*)(ws + 12648448 + 512);
    int* list   = (int*)(ws + 12648448 + 1024);

    hipMemsetAsync(counts, 0, 256, stream); // counts + flag

    k_detect<<<1, 256, 0, stream>>>((const u8*)rst, flag);
    k_packT<<<dim3(32, 96, 2), dim3(32, 8), 0, stream>>>(Wi, Wh, Wit, Wht);
    k_ages<<<256, 256, 0, stream>>>(rst, flag, age, counts);
    k_offsets<<<1, 64, 0, stream>>>(counts, offs, curs);
    k_scatter<<<256, 256, 0, stream>>>(age, curs, list);

    for (int it = 0; it < NITER; ++it)
        k_scan<<<256, 512, 0, stream>>>(it, list, offs, counts, ins, ys, Wit, Wht, bi, bhn);
}

// Round 2
// 2303.304 us; speedup vs baseline: 1.0570x; 1.0570x over previous
//
#include <hip/hip_runtime.h>
#include <stdint.h>

typedef unsigned short u16;
typedef unsigned int u32;
typedef unsigned char u8;

typedef __attribute__((ext_vector_type(4))) float f32x4;
typedef __attribute__((ext_vector_type(4))) u32 u32x4;
typedef __attribute__((ext_vector_type(8))) __bf16 bf16x8;

#define NITER 48
#define BM 128
#define BN 64
#define NKT 32
// LDS layout (u16 elems, row stride 32 = 64 B):
//   A rows 0..255   (x rows 0..127, h rows 128..255)
//   B rows 0..383 at BBASE (row = gate*128 + mat*64 + col_in_block)
#define ABASE 0
#define BBASE 8192
#define LBUF 20480   // u16 per buffer = 40960 B; double-buffered = 81920 B -> 2 blocks/CU

__device__ __forceinline__ u16 f2bf(float f){
    u32 u = __builtin_bit_cast(u32, f);
    u = (u + 0x7FFFu + ((u >> 16) & 1u)) >> 16;
    return (u16)u;
}

__device__ __forceinline__ u32x4 pack8(f32x4 a, f32x4 b){
    u32x4 u;
    u[0] = (u32)f2bf(a[0]) | ((u32)f2bf(a[1]) << 16);
    u[1] = (u32)f2bf(a[2]) | ((u32)f2bf(a[3]) << 16);
    u[2] = (u32)f2bf(b[0]) | ((u32)f2bf(b[1]) << 16);
    u[3] = (u32)f2bf(b[2]) | ((u32)f2bf(b[3]) << 16);
    return u;
}

// ---------- resets dtype detection: 0=int32, 1=bytes(bool), 2=float32 ----------
__global__ void k_detect(const u8* __restrict__ r, int* __restrict__ flag){
    __shared__ int nz[4];
    if (threadIdx.x < 4) nz[threadIdx.x] = 0;
    __syncthreads();
    int loc[4] = {0,0,0,0};
    const int base = threadIdx.x * 16;
    #pragma unroll
    for (int i = 0; i < 16; ++i) if (r[base + i]) loc[i & 3] = 1;
    #pragma unroll
    for (int j = 0; j < 4; ++j) if (loc[j]) atomicOr(&nz[j], 1);
    __syncthreads();
    if (threadIdx.x == 0){
        int f;
        if (nz[0] && !nz[1] && !nz[2] && !nz[3]) f = 0;
        else if (!nz[0] && !nz[1] && (nz[2] || nz[3])) f = 2;
        else f = 1;
        *flag = f;
    }
}

__device__ __forceinline__ int reset_at(const void* r, int f, int idx){
    if (f == 0) return ((const int*)r)[idx] != 0;
    if (f == 1) return ((const u8*)r)[idx] != 0;
    return ((const float*)r)[idx] != 0.f;
}

// ---------- age computation + histogram ----------
__global__ void k_ages(const void* __restrict__ resets, const int* __restrict__ flag,
                       u8* __restrict__ age, int* __restrict__ counts){
    __shared__ int lc[NITER];
    const int tid = threadIdx.x;
    if (tid < NITER) lc[tid] = 0;
    __syncthreads();
    const int id = blockIdx.x * 256 + tid;
    const int f = *flag;
    const int t = id >> 7, b = id & 127;
    int a = 0, tt = t;
    while (tt > 0 && !reset_at(resets, f, tt * 128 + b)){ ++a; --tt; }
    if (a > NITER - 1) a = NITER - 1;
    age[id] = (u8)a;
    atomicAdd(&lc[a], 1);
    __syncthreads();
    if (tid < NITER && lc[tid]) atomicAdd(&counts[tid], lc[tid]);
}

__global__ void k_offsets(const int* __restrict__ counts, int* __restrict__ offs,
                          int* __restrict__ curs){
    if (threadIdx.x == 0){
        int o = 0;
        for (int i = 0; i < NITER; ++i){ offs[i] = o; curs[i] = o; o += counts[i]; }
        offs[NITER] = o;
    }
}

__global__ void k_scatter(const u8* __restrict__ age, int* __restrict__ curs,
                          int* __restrict__ list){
    __shared__ int lc[NITER], lb[NITER];
    const int tid = threadIdx.x;
    if (tid < NITER) lc[tid] = 0;
    __syncthreads();
    const int id = blockIdx.x * 256 + tid;
    const int a = age[id];
    const int lpos = atomicAdd(&lc[a], 1);
    __syncthreads();
    if (tid < NITER && lc[tid]) lb[tid] = atomicAdd(&curs[tid], lc[tid]);
    __syncthreads();
    list[lb[a] + lpos] = id;
}

// ---------- weight pack: Wt[n][k] = bf16(W[k][n]), n<3072, k<1024 ----------
__global__ void k_packT(const float* __restrict__ Wi, const float* __restrict__ Wh,
                        u16* __restrict__ Wit, u16* __restrict__ Wht){
    __shared__ float tl[32][33];
    const int kb = blockIdx.x * 32;
    const int nb = blockIdx.y * 32;
    const float* W = blockIdx.z ? Wh : Wi;
    u16* Wt = blockIdx.z ? Wht : Wit;
    const int tx = threadIdx.x;
    for (int r = threadIdx.y; r < 32; r += 8)
        tl[r][tx] = W[(size_t)(kb + r) * 3072 + nb + tx];
    __syncthreads();
    for (int r = threadIdx.y; r < 32; r += 8)
        Wt[(size_t)(nb + r) * 1024 + kb + tx] = f2bf(tl[tx][r]);
}

// ---------- main wavefront GEMM + fused GRU gates ----------
// 4 waves: wr in {0,1} -> 64 rows each; wc in {0,1} -> 32 hidden cols each.
// Fused acc groups: 0:r (x*Wi_r + h*Wh_r), 1:z, 2:xn, 3:hn  -> 128 acc VGPRs.
__global__ __launch_bounds__(256, 2)
void k_scan(int iter, const int* __restrict__ list, const int* __restrict__ offs,
            const int* __restrict__ counts, const float* __restrict__ ins,
            float* ys, const u16* __restrict__ Wit, const u16* __restrict__ Wht,
            const float* __restrict__ bi, const float* __restrict__ bhn)
{
    const int count = counts[iter];
    if (count <= 0) return;
    const int off = offs[iter];
    const int nMt = (count + BM - 1) / BM;
    const int nTiles = nMt * 16;
    const bool hasH = (iter > 0);

    __shared__ __align__(16) u16 lds[2][LBUF];

    const int tid = threadIdx.x;
    const int lane = tid & 63;
    const int w = tid >> 6;
    const int wr = w >> 1;
    const int wc = w & 1;
    const int l15 = lane & 15;
    const int l4 = lane >> 4;
    const int swz = ((l4 ^ (lane & 3)) * 8);     // read swizzle (u16 elems)

    const int sr = tid >> 2;                     // 0..63 staging row
    const int sq = tid & 3;                      // staging k-slot
    const int swzW = ((sq ^ (sr & 3)) * 8);      // write swizzle (u16 elems)

    for (int tile = blockIdx.x; tile < nTiles; tile += gridDim.x){
        const int mt = tile >> 4;
        const int cg = tile & 15;
        const int m0 = mt * BM;
        const int c0 = cg * BN;

        const int px0i = list[off + min(m0 + sr, count - 1)];
        const int px1i = list[off + min(m0 + 64 + sr, count - 1)];
        const float* px0 = ins + (size_t)px0i * 1024 + sq * 8;
        const float* px1 = ins + (size_t)px1i * 1024 + sq * 8;
        const float* ph0 = ys + (ptrdiff_t)(px0i - 128) * 1024 + sq * 8;
        const float* ph1 = ys + (ptrdiff_t)(px1i - 128) * 1024 + sq * 8;
        const u16* pb[6];
        #pragma unroll
        for (int pp = 0; pp < 6; ++pp){
            const int g = pp >> 1, m = pp & 1;
            const u16* W = m ? Wht : Wit;
            pb[pp] = W + (size_t)(g * 1024 + c0 + sr) * 1024 + sq * 8;
        }

        f32x4 acc[4][4][2];
        #pragma unroll
        for (int gi = 0; gi < 4; ++gi)
            #pragma unroll
            for (int rf = 0; rf < 4; ++rf)
                #pragma unroll
                for (int cf = 0; cf < 2; ++cf)
                    acc[gi][rf][cf] = (f32x4){0.f, 0.f, 0.f, 0.f};

        // ---- prologue: stage k-tile 0 into lds[0]
        {
            u16* N = lds[0];
            *(u32x4*)&N[ABASE + sr * 32 + swzW] =
                pack8(*(const f32x4*)(px0), *(const f32x4*)(px0 + 4));
            *(u32x4*)&N[ABASE + (64 + sr) * 32 + swzW] =
                pack8(*(const f32x4*)(px1), *(const f32x4*)(px1 + 4));
            if (hasH){
                *(u32x4*)&N[ABASE + (128 + sr) * 32 + swzW] =
                    pack8(*(const f32x4*)(ph0), *(const f32x4*)(ph0 + 4));
                *(u32x4*)&N[ABASE + (192 + sr) * 32 + swzW] =
                    pack8(*(const f32x4*)(ph1), *(const f32x4*)(ph1 + 4));
            }
            #pragma unroll
            for (int pp = 0; pp < 6; ++pp)
                *(u32x4*)&N[BBASE + (pp * 64 + sr) * 32 + swzW] = *(const u32x4*)(pb[pp]);
        }
        __syncthreads();

        int cur = 0;
        #pragma unroll 2
        for (int kt = 0; kt < NKT; ++kt){
            // issue next k-tile's global loads early (latency hides under MFMA)
            f32x4 nx0a, nx0b, nx1a, nx1b, nh0a, nh0b, nh1a, nh1b;
            u32x4 sb[6];
            const bool more = (kt < NKT - 1);
            if (more){
                const int kof = (kt + 1) * 32;
                nx0a = *(const f32x4*)(px0 + kof); nx0b = *(const f32x4*)(px0 + kof + 4);
                nx1a = *(const f32x4*)(px1 + kof); nx1b = *(const f32x4*)(px1 + kof + 4);
                if (hasH){
                    nh0a = *(const f32x4*)(ph0 + kof); nh0b = *(const f32x4*)(ph0 + kof + 4);
                    nh1a = *(const f32x4*)(ph1 + kof); nh1b = *(const f32x4*)(ph1 + kof + 4);
                }
                #pragma unroll
                for (int pp = 0; pp < 6; ++pp)
                    sb[pp] = *(const u32x4*)(pb[pp] + kof);
            }

            // ---- compute current k-tile
            const u16* L = lds[cur];
            bf16x8 ax[4], ah[4];
            #pragma unroll
            for (int rf = 0; rf < 4; ++rf){
                const int arow = wr * 64 + rf * 16 + l15;
                ax[rf] = *(const bf16x8*)&L[ABASE + arow * 32 + swz];
            }
            if (hasH){
                #pragma unroll
                for (int rf = 0; rf < 4; ++rf){
                    const int arow = 128 + wr * 64 + rf * 16 + l15;
                    ah[rf] = *(const bf16x8*)&L[ABASE + arow * 32 + swz];
                }
            }
            #pragma unroll
            for (int g = 0; g < 3; ++g){
                #pragma unroll
                for (int cf = 0; cf < 2; ++cf){
                    const int brow = g * 128 + wc * 32 + cf * 16 + l15;
                    bf16x8 bv = *(const bf16x8*)&L[BBASE + brow * 32 + swz];
                    const int gx = (g == 2) ? 2 : g;
                    #pragma unroll
                    for (int rf = 0; rf < 4; ++rf)
                        acc[gx][rf][cf] = __builtin_amdgcn_mfma_f32_16x16x32_bf16(
                            ax[rf], bv, acc[gx][rf][cf], 0, 0, 0);
                    if (hasH){
                        bf16x8 bh = *(const bf16x8*)&L[BBASE + (brow + 64) * 32 + swz];
                        const int gh = (g == 2) ? 3 : g;
                        #pragma unroll
                        for (int rf = 0; rf < 4; ++rf)
                            acc[gh][rf][cf] = __builtin_amdgcn_mfma_f32_16x16x32_bf16(
                                ah[rf], bh, acc[gh][rf][cf], 0, 0, 0);
                    }
                }
            }

            // ---- write staged data into the other buffer (convert late)
            if (more){
                u16* N = lds[cur ^ 1];
                *(u32x4*)&N[ABASE + sr * 32 + swzW] = pack8(nx0a, nx0b);
                *(u32x4*)&N[ABASE + (64 + sr) * 32 + swzW] = pack8(nx1a, nx1b);
                if (hasH){
                    *(u32x4*)&N[ABASE + (128 + sr) * 32 + swzW] = pack8(nh0a, nh0b);
                    *(u32x4*)&N[ABASE + (192 + sr) * 32 + swzW] = pack8(nh1a, nh1b);
                }
                #pragma unroll
                for (int pp = 0; pp < 6; ++pp)
                    *(u32x4*)&N[BBASE + (pp * 64 + sr) * 32 + swzW] = sb[pp];
            }
            __syncthreads();
            cur ^= 1;
        }

        // ---- epilogue: fused GRU gates + output write
        #pragma unroll
        for (int cf = 0; cf < 2; ++cf){
            const int colh = c0 + wc * 32 + cf * 16 + l15;
            const float b_r = bi[colh];
            const float b_z = bi[1024 + colh];
            const float b_n = bi[2048 + colh];
            const float b_h = bhn[colh];
            #pragma unroll
            for (int rf = 0; rf < 4; ++rf){
                #pragma unroll
                for (int m = 0; m < 4; ++m){
                    const int rloc = wr * 64 + rf * 16 + l4 * 4 + m;
                    const int p = list[off + min(m0 + rloc, count - 1)];
                    const float rr = 1.f / (1.f + __expf(-(acc[0][rf][cf][m] + b_r)));
                    const float zz = 1.f / (1.f + __expf(-(acc[1][rf][cf][m] + b_z)));
                    const float nn = tanhf(acc[2][rf][cf][m] + b_n + rr * (acc[3][rf][cf][m] + b_h));
                    float hp = 0.f;
                    if (hasH) hp = ys[(size_t)(p - 128) * 1024 + colh];
                    ys[(size_t)p * 1024 + colh] = (1.f - zz) * nn + zz * hp;
                }
            }
        }
    }
}

extern "C" void kernel_launch(void* const* d_in, const int* in_sizes, int n_in,
                              void* d_out, int out_size, void* d_ws, size_t ws_size,
                              hipStream_t stream)
{
    (void)in_sizes; (void)n_in; (void)out_size; (void)ws_size;
    const float* ins  = (const float*)d_in[0];
    const void*  rst  = d_in[1];
    const float* Wi   = (const float*)d_in[2];
    const float* bi   = (const float*)d_in[3];
    const float* Wh   = (const float*)d_in[4];
    const float* bhn  = (const float*)d_in[5];
    float* ys = (float*)d_out;
    u8* ws = (u8*)d_ws;

    u16* Wit    = (u16*)(ws + 0);
    u16* Wht    = (u16*)(ws + 6291456);
    u8*  age    = ws + 12582912;
    int* counts = (int*)(ws + 12648448);
    int* flag   = (int*)(ws + 12648448 + 192);
    int* offs   = (int*)(ws + 12648448 + 256);
    int* curs   = (int*)(ws + 12648448 + 512);
    int* list   = (int*)(ws + 12648448 + 1024);

    hipMemsetAsync(counts, 0, 256, stream); // counts + flag

    k_detect<<<1, 256, 0, stream>>>((const u8*)rst, flag);
    k_packT<<<dim3(32, 96, 2), dim3(32, 8), 0, stream>>>(Wi, Wh, Wit, Wht);
    k_ages<<<256, 256, 0, stream>>>(rst, flag, age, counts);
    k_offsets<<<1, 64, 0, stream>>>(counts, offs, curs);
    k_scatter<<<256, 256, 0, stream>>>(age, curs, list);

    for (int it = 0; it < NITER; ++it)
        k_scan<<<512, 256, 0, stream>>>(it, list, offs, counts, ins, ys, Wit, Wht, bi, bhn);
}

// Round 3
// 1997.709 us; speedup vs baseline: 1.2187x; 1.1530x over previous
//
#include <hip/hip_runtime.h>
#include <stdint.h>

typedef unsigned short u16;
typedef unsigned int u32;
typedef unsigned char u8;

typedef __attribute__((ext_vector_type(4))) float f32x4;
typedef __attribute__((ext_vector_type(4))) u32 u32x4;
typedef __attribute__((ext_vector_type(8))) __bf16 bf16x8;

#define NITER 48
#define TT 512
#define BB 128

__device__ __forceinline__ u16 f2bf(float f){
    u32 u = __builtin_bit_cast(u32, f);
    u = (u + 0x7FFFu + ((u >> 16) & 1u)) >> 16;
    return (u16)u;
}
__device__ __forceinline__ float bf2f(u16 v){
    u32 u = ((u32)v) << 16;
    return __builtin_bit_cast(float, u);
}
__device__ __forceinline__ u32x4 pack8(f32x4 a, f32x4 b){
    u32x4 u;
    u[0] = (u32)f2bf(a[0]) | ((u32)f2bf(a[1]) << 16);
    u[1] = (u32)f2bf(a[2]) | ((u32)f2bf(a[3]) << 16);
    u[2] = (u32)f2bf(b[0]) | ((u32)f2bf(b[1]) << 16);
    u[3] = (u32)f2bf(b[2]) | ((u32)f2bf(b[3]) << 16);
    return u;
}
__device__ __forceinline__ void glds16(const u16* g, u16* l){
    __builtin_amdgcn_global_load_lds(
        (const __attribute__((address_space(1))) u32*)g,
        (__attribute__((address_space(3))) u32*)l, 16, 0, 0);
}

// ---------- resets dtype detection: 0=int32, 1=bytes(bool), 2=float32 ----------
__global__ void k_detect(const u8* __restrict__ r, int* __restrict__ flag){
    __shared__ int nz[4];
    if (threadIdx.x < 4) nz[threadIdx.x] = 0;
    __syncthreads();
    int loc[4] = {0,0,0,0};
    const int base = threadIdx.x * 16;
    #pragma unroll
    for (int i = 0; i < 16; ++i) if (r[base + i]) loc[i & 3] = 1;
    #pragma unroll
    for (int j = 0; j < 4; ++j) if (loc[j]) atomicOr(&nz[j], 1);
    __syncthreads();
    if (threadIdx.x == 0){
        int f;
        if (nz[0] && !nz[1] && !nz[2] && !nz[3]) f = 0;
        else if (!nz[0] && !nz[1] && (nz[2] || nz[3])) f = 2;
        else f = 1;
        *flag = f;
    }
}

__device__ __forceinline__ int reset_at(const void* r, int f, int idx){
    if (f == 0) return ((const int*)r)[idx] != 0;
    if (f == 1) return ((const u8*)r)[idx] != 0;
    return ((const float*)r)[idx] != 0.f;
}

// ---------- ages per chunk: cid = t*bw + j, global b = b0 + j ----------
__global__ void k_ages(const void* __restrict__ resets, const int* __restrict__ flag,
                       int b0, int bw_log, u8* __restrict__ age, int* __restrict__ counts){
    __shared__ int lc[NITER];
    const int tid = threadIdx.x;
    if (tid < NITER) lc[tid] = 0;
    __syncthreads();
    const int cid = blockIdx.x * 256 + tid;
    const int f = *flag;
    const int bwm = (1 << bw_log) - 1;
    const int t = cid >> bw_log, b = b0 + (cid & bwm);
    int a = 0, tt = t;
    while (tt > 0 && !reset_at(resets, f, tt * BB + b)){ ++a; --tt; }
    if (a > NITER - 1) a = NITER - 1;
    age[cid] = (u8)a;
    atomicAdd(&lc[a], 1);
    __syncthreads();
    if (tid < NITER && lc[tid]) atomicAdd(&counts[tid], lc[tid]);
}

__global__ void k_offsets(const int* __restrict__ counts, int* __restrict__ offs,
                          int* __restrict__ curs){
    if (threadIdx.x == 0){
        int o = 0;
        for (int i = 0; i < NITER; ++i){ offs[i] = o; curs[i] = o; o += counts[i]; }
        offs[NITER] = o;
    }
}

__global__ void k_scatter(const u8* __restrict__ age, int* __restrict__ curs,
                          int* __restrict__ list){
    __shared__ int lc[NITER], lb[NITER];
    const int tid = threadIdx.x;
    if (tid < NITER) lc[tid] = 0;
    __syncthreads();
    const int cid = blockIdx.x * 256 + tid;
    const int a = age[cid];
    const int lpos = atomicAdd(&lc[a], 1);
    __syncthreads();
    if (tid < NITER && lc[tid]) lb[tid] = atomicAdd(&curs[tid], lc[tid]);
    __syncthreads();
    list[lb[a] + lpos] = cid;
}

// ---------- weight pack: Wt[n][k] = bf16(W[k][n]) ----------
__global__ void k_packT(const float* __restrict__ Wi, const float* __restrict__ Wh,
                        u16* __restrict__ Wit, u16* __restrict__ Wht){
    __shared__ float tl[32][33];
    const int kb = blockIdx.x * 32;
    const int nb = blockIdx.y * 32;
    const float* W = blockIdx.z ? Wh : Wi;
    u16* Wt = blockIdx.z ? Wht : Wit;
    const int tx = threadIdx.x;
    for (int r = threadIdx.y; r < 32; r += 8)
        tl[r][tx] = W[(size_t)(kb + r) * 3072 + nb + tx];
    __syncthreads();
    for (int r = threadIdx.y; r < 32; r += 8)
        Wt[(size_t)(nb + r) * 1024 + kb + tx] = f2bf(tl[tx][r]);
}

// ---------- fp32 -> bf16 input conversion (chunk rows, natural cid order) ----------
__global__ void k_tobf(const float* __restrict__ ins, u16* __restrict__ insbf,
                       int b0, int bw_log, int total8){
    const int bwm = (1 << bw_log) - 1;
    for (int i = blockIdx.x * 256 + threadIdx.x; i < total8; i += gridDim.x * 256){
        const int cid = i >> 7;
        const int c8 = (i & 127) * 8;
        const int t = cid >> bw_log, j = cid & bwm;
        const float* src = ins + (size_t)(t * BB + b0 + j) * 1024 + c8;
        f32x4 a = *(const f32x4*)src;
        f32x4 b = *(const f32x4*)(src + 4);
        *(u32x4*)(insbf + (size_t)cid * 1024 + c8) = pack8(a, b);
    }
}

// ---------- xi = insbf @ Wit^T : dense bf16 GEMM, m97-style ----------
// 128x128 tile, 4 waves (2x2), wave 64x64, BK=32, global_load_lds staging.
__global__ __launch_bounds__(256, 4)
void k_xi(const u16* __restrict__ insbf, const u16* __restrict__ Wit,
          u16* __restrict__ xi, int Mrows)
{
    __shared__ __align__(16) u16 lds[2][8192]; // per buf: A[0..4095] B[4096..8191]
    const int tid = threadIdx.x;
    const int lane = tid & 63;
    const int w = tid >> 6;
    const int wr = w >> 1, wc = w & 1;
    const int l15 = lane & 15;
    const int l4 = lane >> 4;
    const int srow = lane >> 2;     // 0..15 within wave
    const int slot = lane & 3;

    const int nMt = Mrows >> 7;
    const int nTiles = nMt * 24;

    for (int tile = blockIdx.x; tile < nTiles; tile += gridDim.x){
        const int mt = tile / 24;
        const int cg = tile - mt * 24;
        const int m0 = mt * 128;
        const int c0 = cg * 128;

        const u16* ga0 = insbf + (size_t)(m0 + w * 16 + srow) * 1024 + slot * 8;
        const u16* ga1 = ga0 + (size_t)64 * 1024;
        const u16* gb0 = Wit + (size_t)(c0 + w * 16 + srow) * 1024 + slot * 8;
        const u16* gb1 = gb0 + (size_t)64 * 1024;

        f32x4 acc[4][4];
        #pragma unroll
        for (int i = 0; i < 4; ++i)
            #pragma unroll
            for (int j = 0; j < 4; ++j)
                acc[i][j] = (f32x4){0.f, 0.f, 0.f, 0.f};

        // prologue: stage k-tile 0
        {
            u16* Lb = lds[0];
            glds16(ga0, &Lb[w * 512]);
            glds16(ga1, &Lb[2048 + w * 512]);
            glds16(gb0, &Lb[4096 + w * 512]);
            glds16(gb1, &Lb[6144 + w * 512]);
        }
        __syncthreads();

        for (int kt = 0; kt < 32; ++kt){
            if (kt < 31){
                u16* Nb = lds[(kt + 1) & 1];
                const int ko = (kt + 1) * 32;
                glds16(ga0 + ko, &Nb[w * 512]);
                glds16(ga1 + ko, &Nb[2048 + w * 512]);
                glds16(gb0 + ko, &Nb[4096 + w * 512]);
                glds16(gb1 + ko, &Nb[6144 + w * 512]);
            }
            const u16* L = lds[kt & 1];
            bf16x8 ax[4], bx[4];
            #pragma unroll
            for (int rf = 0; rf < 4; ++rf)
                ax[rf] = *(const bf16x8*)&L[(wr * 64 + rf * 16 + l15) * 32 + l4 * 8];
            #pragma unroll
            for (int cf = 0; cf < 4; ++cf)
                bx[cf] = *(const bf16x8*)&L[4096 + (wc * 64 + cf * 16 + l15) * 32 + l4 * 8];
            #pragma unroll
            for (int rf = 0; rf < 4; ++rf)
                #pragma unroll
                for (int cf = 0; cf < 4; ++cf)
                    acc[rf][cf] = __builtin_amdgcn_mfma_f32_16x16x32_bf16(
                        ax[rf], bx[cf], acc[rf][cf], 0, 0, 0);
            __syncthreads();
        }

        // epilogue: per-wave 64x64 bf16 tile via LDS, then coalesced 16B stores
        u16* region = ((u16*)lds) + w * 4096;
        #pragma unroll
        for (int rf = 0; rf < 4; ++rf)
            #pragma unroll
            for (int cf = 0; cf < 4; ++cf)
                #pragma unroll
                for (int m = 0; m < 4; ++m)
                    region[(rf * 16 + l4 * 4 + m) * 64 + cf * 16 + l15] = f2bf(acc[rf][cf][m]);
        #pragma unroll
        for (int rep = 0; rep < 8; ++rep){
            const int r = rep * 8 + (lane >> 3);
            const int cc = (lane & 7) * 8;
            u32x4 v = *(u32x4*)&region[r * 64 + cc];
            *(u32x4*)(xi + (size_t)(m0 + wr * 64 + r) * 3072 + c0 + wc * 64 + cc) = v;
        }
        __syncthreads();
    }
}

// ---------- age-0 rows: pure elementwise gates (h_prev = 0) ----------
__global__ void k_h0(const int* __restrict__ list, const int* __restrict__ counts,
                     const u16* __restrict__ xi, float* __restrict__ ys,
                     const float* __restrict__ bi, const float* __restrict__ bhn,
                     int b0, int bw_log)
{
    const int total = counts[0] * 128;
    const int bwm = (1 << bw_log) - 1;
    for (int i = blockIdx.x * 256 + threadIdx.x; i < total; i += gridDim.x * 256){
        const int row = i >> 7;
        const int c8 = (i & 127) * 8;
        const int cid = list[row];
        const int p = ((cid >> bw_log) << 7) + b0 + (cid & bwm);
        const u16* xr = xi + (size_t)cid * 3072 + c8;
        u32x4 vr = *(const u32x4*)xr;
        u32x4 vz = *(const u32x4*)(xr + 1024);
        u32x4 vn = *(const u32x4*)(xr + 2048);
        f32x4 br0 = *(const f32x4*)(bi + c8),        br1 = *(const f32x4*)(bi + c8 + 4);
        f32x4 bz0 = *(const f32x4*)(bi + 1024 + c8), bz1 = *(const f32x4*)(bi + 1024 + c8 + 4);
        f32x4 bn0 = *(const f32x4*)(bi + 2048 + c8), bn1 = *(const f32x4*)(bi + 2048 + c8 + 4);
        f32x4 bh0 = *(const f32x4*)(bhn + c8),       bh1 = *(const f32x4*)(bhn + c8 + 4);
        float out[8];
        #pragma unroll
        for (int e = 0; e < 8; ++e){
            const float xrv = bf2f((u16)(vr[e >> 1] >> ((e & 1) * 16)));
            const float xzv = bf2f((u16)(vz[e >> 1] >> ((e & 1) * 16)));
            const float xnv = bf2f((u16)(vn[e >> 1] >> ((e & 1) * 16)));
            const float brv = (e < 4) ? br0[e] : br1[e - 4];
            const float bzv = (e < 4) ? bz0[e] : bz1[e - 4];
            const float bnv = (e < 4) ? bn0[e] : bn1[e - 4];
            const float bhv = (e < 4) ? bh0[e] : bh1[e - 4];
            const float rr = 1.f / (1.f + __expf(-(xrv + brv)));
            const float zz = 1.f / (1.f + __expf(-(xzv + bzv)));
            const float nn = tanhf(xnv + bnv + rr * bhv);
            out[e] = (1.f - zz) * nn;
        }
        float* dst = ys + (size_t)p * 1024 + c8;
        *(f32x4*)dst = (f32x4){out[0], out[1], out[2], out[3]};
        *(f32x4*)(dst + 4) = (f32x4){out[4], out[5], out[6], out[7]};
    }
}

// ---------- h-side scan GEMM + fused gates (iters >= 1) ----------
// 4 waves 2x2; BM=128 rows, BN=64 cols; acc groups hr,hz,hn.
#define SABASE 0
#define SBBASE 4096
#define SLBUF 10240
__global__ __launch_bounds__(256, 3)
void k_scanh(int iter, const int* __restrict__ list, const int* __restrict__ offs,
             const int* __restrict__ counts, const u16* __restrict__ xi,
             float* ys, const u16* __restrict__ Wht,
             const float* __restrict__ bi, const float* __restrict__ bhn,
             int b0, int bw_log)
{
    const int count = counts[iter];
    if (count <= 0) return;
    const int off = offs[iter];
    const int nMt = (count + 127) >> 7;
    const int nTiles = nMt * 16;
    const int bwm = (1 << bw_log) - 1;

    __shared__ __align__(16) u16 lds[2][SLBUF];

    const int tid = threadIdx.x;
    const int lane = tid & 63;
    const int w = tid >> 6;
    const int wr = w >> 1;
    const int wc = w & 1;
    const int l15 = lane & 15;
    const int l4 = lane >> 4;
    const int swz = ((l4 ^ (lane & 3)) * 8);
    const int sr = tid >> 2;
    const int sq = tid & 3;
    const int swzW = ((sq ^ (sr & 3)) * 8);

    for (int tile = blockIdx.x; tile < nTiles; tile += gridDim.x){
        const int mt = tile >> 4;
        const int cg = tile & 15;
        const int m0 = mt * 128;
        const int c0 = cg * 64;

        const int cid0 = list[off + min(m0 + sr, count - 1)];
        const int cid1 = list[off + min(m0 + 64 + sr, count - 1)];
        const int p0 = ((cid0 >> bw_log) << 7) + b0 + (cid0 & bwm);
        const int p1 = ((cid1 >> bw_log) << 7) + b0 + (cid1 & bwm);
        const float* ph0 = ys + (size_t)(p0 - 128) * 1024 + sq * 8;
        const float* ph1 = ys + (size_t)(p1 - 128) * 1024 + sq * 8;
        const u16* pb[3];
        #pragma unroll
        for (int g = 0; g < 3; ++g)
            pb[g] = Wht + (size_t)(g * 1024 + c0 + sr) * 1024 + sq * 8;

        f32x4 acc[3][4][2];
        #pragma unroll
        for (int gi = 0; gi < 3; ++gi)
            #pragma unroll
            for (int rf = 0; rf < 4; ++rf)
                #pragma unroll
                for (int cf = 0; cf < 2; ++cf)
                    acc[gi][rf][cf] = (f32x4){0.f, 0.f, 0.f, 0.f};

        { // prologue k-tile 0
            u16* N = lds[0];
            *(u32x4*)&N[SABASE + sr * 32 + swzW] =
                pack8(*(const f32x4*)(ph0), *(const f32x4*)(ph0 + 4));
            *(u32x4*)&N[SABASE + (64 + sr) * 32 + swzW] =
                pack8(*(const f32x4*)(ph1), *(const f32x4*)(ph1 + 4));
            #pragma unroll
            for (int g = 0; g < 3; ++g)
                *(u32x4*)&N[SBBASE + (g * 64 + sr) * 32 + swzW] = *(const u32x4*)(pb[g]);
        }
        __syncthreads();

        int cur = 0;
        #pragma unroll 2
        for (int kt = 0; kt < 32; ++kt){
            f32x4 nh0a, nh0b, nh1a, nh1b;
            u32x4 sb[3];
            const bool more = (kt < 31);
            if (more){
                const int kof = (kt + 1) * 32;
                nh0a = *(const f32x4*)(ph0 + kof); nh0b = *(const f32x4*)(ph0 + kof + 4);
                nh1a = *(const f32x4*)(ph1 + kof); nh1b = *(const f32x4*)(ph1 + kof + 4);
                #pragma unroll
                for (int g = 0; g < 3; ++g) sb[g] = *(const u32x4*)(pb[g] + kof);
            }

            const u16* L = lds[cur];
            bf16x8 ah[4];
            #pragma unroll
            for (int rf = 0; rf < 4; ++rf)
                ah[rf] = *(const bf16x8*)&L[SABASE + (wr * 64 + rf * 16 + l15) * 32 + swz];
            #pragma unroll
            for (int g = 0; g < 3; ++g){
                #pragma unroll
                for (int cf = 0; cf < 2; ++cf){
                    bf16x8 bh = *(const bf16x8*)&L[SBBASE + (g * 64 + wc * 32 + cf * 16 + l15) * 32 + swz];
                    #pragma unroll
                    for (int rf = 0; rf < 4; ++rf)
                        acc[g][rf][cf] = __builtin_amdgcn_mfma_f32_16x16x32_bf16(
                            ah[rf], bh, acc[g][rf][cf], 0, 0, 0);
                }
            }

            if (more){
                u16* N = lds[cur ^ 1];
                *(u32x4*)&N[SABASE + sr * 32 + swzW] = pack8(nh0a, nh0b);
                *(u32x4*)&N[SABASE + (64 + sr) * 32 + swzW] = pack8(nh1a, nh1b);
                #pragma unroll
                for (int g = 0; g < 3; ++g)
                    *(u32x4*)&N[SBBASE + (g * 64 + sr) * 32 + swzW] = sb[g];
            }
            __syncthreads();
            cur ^= 1;
        }

        // epilogue
        #pragma unroll
        for (int cf = 0; cf < 2; ++cf){
            const int colh = c0 + wc * 32 + cf * 16 + l15;
            const float b_r = bi[colh];
            const float b_z = bi[1024 + colh];
            const float b_n = bi[2048 + colh];
            const float b_h = bhn[colh];
            #pragma unroll
            for (int rf = 0; rf < 4; ++rf){
                #pragma unroll
                for (int m = 0; m < 4; ++m){
                    const int rloc = wr * 64 + rf * 16 + l4 * 4 + m;
                    const int cid = list[off + min(m0 + rloc, count - 1)];
                    const int p = ((cid >> bw_log) << 7) + b0 + (cid & bwm);
                    const u16* xr = xi + (size_t)cid * 3072 + colh;
                    const float rr = 1.f / (1.f + __expf(-(bf2f(xr[0]) + b_r + acc[0][rf][cf][m])));
                    const float zz = 1.f / (1.f + __expf(-(bf2f(xr[1024]) + b_z + acc[1][rf][cf][m])));
                    const float nn = tanhf(bf2f(xr[2048]) + b_n + rr * (acc[2][rf][cf][m] + b_h));
                    const float hp = ys[(size_t)(p - 128) * 1024 + colh];
                    ys[(size_t)p * 1024 + colh] = (1.f - zz) * nn + zz * hp;
                }
            }
        }
    }
}

// ---------- fallback: round-2 fused x+h kernel (used when ws is small) ----------
__global__ __launch_bounds__(256, 2)
void k_scan_fb(int iter, const int* __restrict__ list, const int* __restrict__ offs,
               const int* __restrict__ counts, const float* __restrict__ ins,
               float* ys, const u16* __restrict__ Wit, const u16* __restrict__ Wht,
               const float* __restrict__ bi, const float* __restrict__ bhn)
{
    const int count = counts[iter];
    if (count <= 0) return;
    const int off = offs[iter];
    const int nMt = (count + 127) >> 7;
    const int nTiles = nMt * 16;
    const bool hasH = (iter > 0);

    __shared__ __align__(16) u16 lds[2][20480];

    const int tid = threadIdx.x;
    const int lane = tid & 63;
    const int w = tid >> 6;
    const int wr = w >> 1;
    const int wc = w & 1;
    const int l15 = lane & 15;
    const int l4 = lane >> 4;
    const int swz = ((l4 ^ (lane & 3)) * 8);
    const int sr = tid >> 2;
    const int sq = tid & 3;
    const int swzW = ((sq ^ (sr & 3)) * 8);

    for (int tile = blockIdx.x; tile < nTiles; tile += gridDim.x){
        const int mt = tile >> 4;
        const int cg = tile & 15;
        const int m0 = mt * 128;
        const int c0 = cg * 64;

        const int px0i = list[off + min(m0 + sr, count - 1)];
        const int px1i = list[off + min(m0 + 64 + sr, count - 1)];
        const float* px0 = ins + (size_t)px0i * 1024 + sq * 8;
        const float* px1 = ins + (size_t)px1i * 1024 + sq * 8;
        const float* ph0 = ys + (ptrdiff_t)(px0i - 128) * 1024 + sq * 8;
        const float* ph1 = ys + (ptrdiff_t)(px1i - 128) * 1024 + sq * 8;
        const u16* pb[6];
        #pragma unroll
        for (int pp = 0; pp < 6; ++pp){
            const int g = pp >> 1, m = pp & 1;
            const u16* W = m ? Wht : Wit;
            pb[pp] = W + (size_t)(g * 1024 + c0 + sr) * 1024 + sq * 8;
        }

        f32x4 acc[4][4][2];
        #pragma unroll
        for (int gi = 0; gi < 4; ++gi)
            #pragma unroll
            for (int rf = 0; rf < 4; ++rf)
                #pragma unroll
                for (int cf = 0; cf < 2; ++cf)
                    acc[gi][rf][cf] = (f32x4){0.f, 0.f, 0.f, 0.f};

        {
            u16* N = lds[0];
            *(u32x4*)&N[sr * 32 + swzW] = pack8(*(const f32x4*)(px0), *(const f32x4*)(px0 + 4));
            *(u32x4*)&N[(64 + sr) * 32 + swzW] = pack8(*(const f32x4*)(px1), *(const f32x4*)(px1 + 4));
            if (hasH){
                *(u32x4*)&N[(128 + sr) * 32 + swzW] = pack8(*(const f32x4*)(ph0), *(const f32x4*)(ph0 + 4));
                *(u32x4*)&N[(192 + sr) * 32 + swzW] = pack8(*(const f32x4*)(ph1), *(const f32x4*)(ph1 + 4));
            }
            #pragma unroll
            for (int pp = 0; pp < 6; ++pp)
                *(u32x4*)&N[8192 + (pp * 64 + sr) * 32 + swzW] = *(const u32x4*)(pb[pp]);
        }
        __syncthreads();

        int cur = 0;
        #pragma unroll 2
        for (int kt = 0; kt < 32; ++kt){
            f32x4 nx0a, nx0b, nx1a, nx1b, nh0a, nh0b, nh1a, nh1b;
            u32x4 sb[6];
            const bool more = (kt < 31);
            if (more){
                const int kof = (kt + 1) * 32;
                nx0a = *(const f32x4*)(px0 + kof); nx0b = *(const f32x4*)(px0 + kof + 4);
                nx1a = *(const f32x4*)(px1 + kof); nx1b = *(const f32x4*)(px1 + kof + 4);
                if (hasH){
                    nh0a = *(const f32x4*)(ph0 + kof); nh0b = *(const f32x4*)(ph0 + kof + 4);
                    nh1a = *(const f32x4*)(ph1 + kof); nh1b = *(const f32x4*)(ph1 + kof + 4);
                }
                #pragma unroll
                for (int pp = 0; pp < 6; ++pp) sb[pp] = *(const u32x4*)(pb[pp] + kof);
            }

            const u16* L = lds[cur];
            bf16x8 ax[4], ah[4];
            #pragma unroll
            for (int rf = 0; rf < 4; ++rf)
                ax[rf] = *(const bf16x8*)&L[(wr * 64 + rf * 16 + l15) * 32 + swz];
            if (hasH){
                #pragma unroll
                for (int rf = 0; rf < 4; ++rf)
                    ah[rf] = *(const bf16x8*)&L[(128 + wr * 64 + rf * 16 + l15) * 32 + swz];
            }
            #pragma unroll
            for (int g = 0; g < 3; ++g){
                #pragma unroll
                for (int cf = 0; cf < 2; ++cf){
                    const int brow = g * 128 + wc * 32 + cf * 16 + l15;
                    bf16x8 bv = *(const bf16x8*)&L[8192 + brow * 32 + swz];
                    const int gx = (g == 2) ? 2 : g;
                    #pragma unroll
                    for (int rf = 0; rf < 4; ++rf)
                        acc[gx][rf][cf] = __builtin_amdgcn_mfma_f32_16x16x32_bf16(
                            ax[rf], bv, acc[gx][rf][cf], 0, 0, 0);
                    if (hasH){
                        bf16x8 bh = *(const bf16x8*)&L[8192 + (brow + 64) * 32 + swz];
                        const int gh = (g == 2) ? 3 : g;
                        #pragma unroll
                        for (int rf = 0; rf < 4; ++rf)
                            acc[gh][rf][cf] = __builtin_amdgcn_mfma_f32_16x16x32_bf16(
                                ah[rf], bh, acc[gh][rf][cf], 0, 0, 0);
                    }
                }
            }

            if (more){
                u16* N = lds[cur ^ 1];
                *(u32x4*)&N[sr * 32 + swzW] = pack8(nx0a, nx0b);
                *(u32x4*)&N[(64 + sr) * 32 + swzW] = pack8(nx1a, nx1b);
                if (hasH){
                    *(u32x4*)&N[(128 + sr) * 32 + swzW] = pack8(nh0a, nh0b);
                    *(u32x4*)&N[(192 + sr) * 32 + swzW] = pack8(nh1a, nh1b);
                }
                #pragma unroll
                for (int pp = 0; pp < 6; ++pp)
                    *(u32x4*)&N[8192 + (pp * 64 + sr) * 32 + swzW] = sb[pp];
            }
            __syncthreads();
            cur ^= 1;
        }

        #pragma unroll
        for (int cf = 0; cf < 2; ++cf){
            const int colh = c0 + wc * 32 + cf * 16 + l15;
            const float b_r = bi[colh];
            const float b_z = bi[1024 + colh];
            const float b_n = bi[2048 + colh];
            const float b_h = bhn[colh];
            #pragma unroll
            for (int rf = 0; rf < 4; ++rf){
                #pragma unroll
                for (int m = 0; m < 4; ++m){
                    const int rloc = wr * 64 + rf * 16 + l4 * 4 + m;
                    const int p = list[off + min(m0 + rloc, count - 1)];
                    const float rr = 1.f / (1.f + __expf(-(acc[0][rf][cf][m] + b_r)));
                    const float zz = 1.f / (1.f + __expf(-(acc[1][rf][cf][m] + b_z)));
                    const float nn = tanhf(acc[2][rf][cf][m] + b_n + rr * (acc[3][rf][cf][m] + b_h));
                    float hp = 0.f;
                    if (hasH) hp = ys[(size_t)(p - 128) * 1024 + colh];
                    ys[(size_t)p * 1024 + colh] = (1.f - zz) * nn + zz * hp;
                }
            }
        }
    }
}

extern "C" void kernel_launch(void* const* d_in, const int* in_sizes, int n_in,
                              void* d_out, int out_size, void* d_ws, size_t ws_size,
                              hipStream_t stream)
{
    (void)in_sizes; (void)n_in; (void)out_size;
    const float* ins  = (const float*)d_in[0];
    const void*  rst  = d_in[1];
    const float* Wi   = (const float*)d_in[2];
    const float* bi   = (const float*)d_in[3];
    const float* Wh   = (const float*)d_in[4];
    const float* bhn  = (const float*)d_in[5];
    float* ys = (float*)d_out;
    u8* ws = (u8*)d_ws;

    u16* Wit    = (u16*)(ws + 0);
    u16* Wht    = (u16*)(ws + 6291456);
    u8*  age    = ws + 12582912;
    int* counts = (int*)(ws + 12648448);
    int* offs   = (int*)(ws + 12648704);
    int* curs   = (int*)(ws + 12648960);
    int* flag   = (int*)(ws + 12649216);
    int* list   = (int*)(ws + 12649472);
    u16* insbf  = (u16*)(ws + 12911616);

    // choose batch-chunking per available workspace
    int bw = 0, bwlog = 0;
    {
        const size_t base = 12911616;
        if (ws_size >= base + (size_t)TT * 128 * 8192)      { bw = 128; bwlog = 7; }
        else if (ws_size >= base + (size_t)TT * 64 * 8192)  { bw = 64;  bwlog = 6; }
        else if (ws_size >= base + (size_t)TT * 32 * 8192)  { bw = 32;  bwlog = 5; }
    }

    k_detect<<<1, 256, 0, stream>>>((const u8*)rst, flag);
    k_packT<<<dim3(32, 96, 2), dim3(32, 8), 0, stream>>>(Wi, Wh, Wit, Wht);

    if (bw == 0){
        // fallback: fused x+h scan over full batch
        hipMemsetAsync(counts, 0, 192, stream);
        k_ages<<<TT * BB / 256, 256, 0, stream>>>(rst, flag, 0, 7, age, counts);
        k_offsets<<<1, 64, 0, stream>>>(counts, offs, curs);
        k_scatter<<<TT * BB / 256, 256, 0, stream>>>(age, curs, list);
        for (int it = 0; it < NITER; ++it)
            k_scan_fb<<<512, 256, 0, stream>>>(it, list, offs, counts, ins, ys, Wit, Wht, bi, bhn);
        return;
    }

    u16* xi = insbf + (size_t)TT * bw * 1024;
    const int nch = BB / bw;
    const int Mrows = TT * bw;

    for (int c = 0; c < nch; ++c){
        const int b0 = c * bw;
        hipMemsetAsync(counts, 0, 192, stream);
        k_ages<<<Mrows / 256, 256, 0, stream>>>(rst, flag, b0, bwlog, age, counts);
        k_offsets<<<1, 64, 0, stream>>>(counts, offs, curs);
        k_scatter<<<Mrows / 256, 256, 0, stream>>>(age, curs, list);
        k_tobf<<<2048, 256, 0, stream>>>(ins, insbf, b0, bwlog, Mrows * 128);
        k_xi<<<3072, 256, 0, stream>>>(insbf, Wit, xi, Mrows);
        k_h0<<<2048, 256, 0, stream>>>(list, counts, xi, ys, bi, bhn, b0, bwlog);
        for (int it = 1; it < NITER; ++it)
            k_scanh<<<512, 256, 0, stream>>>(it, list, offs, counts, xi, ys, Wht, bi, bhn, b0, bwlog);
    }
}